// Round 1
// baseline (4055.186 us; speedup 1.0000x reference)
//
#include <hip/hip_runtime.h>
#include <hip/hip_bf16.h>

// Problem constants
#define BB 8
#define CC_ 128
#define HH 128
#define WW 128
#define EE 3

// ---------------------------------------------------------------------------
// Weight transpose kernels: put 'co' innermost for coalesced broadcast loads.
// ---------------------------------------------------------------------------
__global__ void t1_kernel(const float* __restrict__ w, float* __restrict__ wT) {
    // a_c1w [256][128][9] -> wT1 [128cc][9tap][256co]
    int i = blockIdx.x * 256 + threadIdx.x;
    if (i >= 256 * 128 * 9) return;
    int tap = i % 9;
    int cc = (i / 9) % 128;
    int co = i / (9 * 128);
    wT[(cc * 9 + tap) * 256 + co] = w[i];
}

__global__ void te_kernel(const float* __restrict__ w, float* __restrict__ wT) {
    // ew [3][128co][128cc][9] -> wT [3][128cc][9][128co]
    int i = blockIdx.x * 256 + threadIdx.x;
    if (i >= 3 * 128 * 128 * 9) return;
    int tap = i % 9;
    int cc = (i / 9) % 128;
    int co = (i / (9 * 128)) % 128;
    int e = i / (9 * 128 * 128);
    wT[((e * 128 + cc) * 9 + tap) * 128 + co] = w[i];
}

__global__ void t3_kernel(const float* __restrict__ w, float* __restrict__ wT) {
    // ew3 [3][128co][128cc] -> wT3 [3][128cc][128co]
    int i = blockIdx.x * 256 + threadIdx.x;
    if (i >= 3 * 128 * 128) return;
    int cc = i % 128;
    int co = (i / 128) % 128;
    int e = i / (128 * 128);
    wT[(e * 128 + cc) * 128 + co] = w[i];
}

// ---------------------------------------------------------------------------
// K1: y = conv3x3(|x|, a_c1w) + a_c1b  -> xh (bf16), k (bf16), per-(b,c) sums
// block: 128 threads, tile = 1 row x 32 cols. thread: ph=t&1 (16 px), cb=t>>1,
// covers co = cb + 64*q, q=0..3.
// ---------------------------------------------------------------------------
__global__ __launch_bounds__(128) void conv1_kernel(
    const float* __restrict__ x, const float* __restrict__ wT,
    const float* __restrict__ bias,
    __hip_bfloat16* __restrict__ xh, __hip_bfloat16* __restrict__ kk,
    float* __restrict__ meansum)
{
    const int b = blockIdx.z, h = blockIdx.y, w0 = blockIdx.x * 32;
    const int t = threadIdx.x;
    const int ph = t & 1, cb = t >> 1;      // cb 0..63
    __shared__ float sx[8][3][36];
    float acc[4][16];
#pragma unroll
    for (int q = 0; q < 4; q++)
#pragma unroll
        for (int p = 0; p < 16; p++) acc[q][p] = 0.f;

    const float* xb = x + (size_t)b * CC_ * HH * WW;

    for (int c0 = 0; c0 < 128; c0 += 8) {
        __syncthreads();
        for (int i = t; i < 816; i += 128) {   // 8*3*34
            int col = i % 34;
            int rr = (i / 34) % 3;
            int cc = i / 102;
            int gh = h + rr - 1, gw2 = w0 + col - 1;
            float v = 0.f;
            if ((unsigned)gh < 128u && (unsigned)gw2 < 128u)
                v = fabsf(xb[((size_t)(c0 + cc) * 128 + gh) * 128 + gw2]);
            sx[cc][rr][col] = v;
        }
        __syncthreads();
#pragma unroll 1
        for (int cc = 0; cc < 8; cc++) {
            const float* wp = wT + (size_t)(c0 + cc) * 9 * 256 + cb;
#pragma unroll
            for (int r = 0; r < 3; r++) {
                float xv[18];
#pragma unroll
                for (int j = 0; j < 18; j++) xv[j] = sx[cc][r][ph * 16 + j];
#pragma unroll
                for (int j = 0; j < 3; j++) {
                    const float* wq = wp + (r * 3 + j) * 256;
                    float wv0 = wq[0], wv1 = wq[64], wv2 = wq[128], wv3 = wq[192];
#pragma unroll
                    for (int p = 0; p < 16; p++) {
                        float xvv = xv[p + j];
                        acc[0][p] += xvv * wv0;
                        acc[1][p] += xvv * wv1;
                        acc[2][p] += xvv * wv2;
                        acc[3][p] += xvv * wv3;
                    }
                }
            }
        }
    }

    const int wbase = w0 + ph * 16;
#pragma unroll
    for (int q = 0; q < 4; q++) {
        int co = cb + q * 64;
        float bv = bias[co];
        if (co < 128) {
            size_t base = (((size_t)b * 128 + co) * 128 + h) * 128 + wbase;
            float s = 0.f;
#pragma unroll
            for (int p = 0; p < 16; p++) {
                float y = acc[q][p] + bv;
                s += y;
                xh[base + p] = __float2bfloat16(y);
            }
            atomicAdd(&meansum[b * 128 + co], s);
        } else {
            size_t base = (((size_t)b * 128 + (co - 128)) * 128 + h) * 128 + wbase;
#pragma unroll
            for (int p = 0; p < 16; p++)
                kk[base + p] = __float2bfloat16(acc[q][p] + bv);
        }
    }
}

// ---------------------------------------------------------------------------
// K2: gating for fem_a. logits = mean(xh) @ gw.T ; softmax ; top-2 mask.
// top_k tie rule: on ties keeps lower index => drop argmin with ties dropping
// the LARGER index.
// ---------------------------------------------------------------------------
__global__ void gate_kernel(const float* __restrict__ meansum,
                            const float* __restrict__ gw,
                            float* __restrict__ gate)
{
    int b = threadIdx.x;
    if (b >= 8) return;
    float l[3];
    for (int e = 0; e < 3; e++) {
        float s = 0.f;
        for (int c = 0; c < 128; c++) s += meansum[b * 128 + c] * gw[e * 128 + c];
        l[e] = s * (1.0f / 16384.0f);
    }
    float m = fmaxf(l[0], fmaxf(l[1], l[2]));
    float p0 = expf(l[0] - m), p1 = expf(l[1] - m), p2 = expf(l[2] - m);
    float s = p0 + p1 + p2;
    float w[3] = { p0 / s, p1 / s, p2 / s };
    int dm = 0;
    if (w[1] <= w[0]) dm = 1;
    if (w[2] <= w[dm]) dm = 2;
    for (int e = 0; e < 3; e++) gate[b * 3 + e] = (e == dm) ? 0.f : w[e];
}

// ---------------------------------------------------------------------------
// K3: fem_b on zero input collapses to a batch-independent [C][9-region] map.
// region = rclass*3 + cclass; class 0 = first row/col, 1 = interior, 2 = last.
// ---------------------------------------------------------------------------
__global__ __launch_bounds__(128) void out2_kernel(
    const float* __restrict__ c1b, const float* __restrict__ gw,
    const float* __restrict__ ew1, const float* __restrict__ eb1,
    const float* __restrict__ ew2, const float* __restrict__ eb2,
    const float* __restrict__ ew3, const float* __restrict__ eb3,
    float* __restrict__ out2map)
{
    __shared__ float sxh[128], skk[128];
    __shared__ float sprod[3][128][9];
    int c = threadIdx.x;
    sxh[c] = c1b[c];
    skk[c] = c1b[128 + c];
    __syncthreads();

    for (int e = 0; e < 3; e++) {
        float A[9], Bv[9];
#pragma unroll
        for (int tp = 0; tp < 9; tp++) { A[tp] = 0.f; Bv[tp] = 0.f; }
        for (int cc = 0; cc < 128; cc++) {
            float xv = sxh[cc], kv = skk[cc];
            const float* w1 = ew1 + ((size_t)(e * 128 + c) * 128 + cc) * 9;
            const float* w2 = ew2 + ((size_t)(e * 128 + c) * 128 + cc) * 9;
#pragma unroll
            for (int tp = 0; tp < 9; tp++) {
                A[tp] += xv * w1[tp];
                Bv[tp] += kv * w2[tp];
            }
        }
        float b1 = eb1[e * 128 + c], b2 = eb2[e * 128 + c];
        for (int rcl = 0; rcl < 3; rcl++) {
            for (int ccl = 0; ccl < 3; ccl++) {
                float av = b1, bv = b2;
#pragma unroll
                for (int i = 0; i < 3; i++) {
#pragma unroll
                    for (int j = 0; j < 3; j++) {
                        bool iok = (rcl == 1) || (rcl == 0 && i >= 1) || (rcl == 2 && i <= 1);
                        bool jok = (ccl == 1) || (ccl == 0 && j >= 1) || (ccl == 2 && j <= 1);
                        if (iok && jok) { av += A[i * 3 + j]; bv += Bv[i * 3 + j]; }
                    }
                }
                sprod[e][c][rcl * 3 + ccl] = av * bv;
            }
        }
    }
    __syncthreads();

    float eo[3][9];
    for (int e = 0; e < 3; e++) {
        float b3 = eb3[e * 128 + c];
#pragma unroll
        for (int r = 0; r < 9; r++) eo[e][r] = b3;
        for (int cc = 0; cc < 128; cc++) {
            float wv = ew3[(size_t)(e * 128 + c) * 128 + cc];
#pragma unroll
            for (int r = 0; r < 9; r++) eo[e][r] += wv * sprod[e][cc][r];
        }
    }

    // batch-invariant gating for fem_b
    float l[3];
    for (int e = 0; e < 3; e++) {
        float s = 0.f;
        for (int cc = 0; cc < 128; cc++) s += sxh[cc] * gw[e * 128 + cc];
        l[e] = s;
    }
    float m = fmaxf(l[0], fmaxf(l[1], l[2]));
    float p0 = expf(l[0] - m), p1 = expf(l[1] - m), p2 = expf(l[2] - m);
    float ssum = p0 + p1 + p2;
    float wv[3] = { p0 / ssum, p1 / ssum, p2 / ssum };
    int dm = 0;
    if (wv[1] <= wv[0]) dm = 1;
    if (wv[2] <= wv[dm]) dm = 2;
    wv[dm] = 0.f;

    for (int r = 0; r < 9; r++) {
        float o = sxh[c];
        for (int e = 0; e < 3; e++) o += wv[e] * eo[e][r];
        out2map[c * 9 + r] = o;
    }
}

// ---------------------------------------------------------------------------
// K4: per-batch top-2 experts: a = conv3x3(xh,w1)+b1, bb = conv3x3(k,w2)+b2,
// eo = conv1x1(a*bb,w3)+b3 ; out = xh + sum w_e*eo_e + out2map + x.
// block: 128 threads, tile 1x32. thread: ph=t&1 (16 px), cb=t>>1,
// channels c = cb, cb+64.
// ---------------------------------------------------------------------------
__global__ __launch_bounds__(128) void expert_kernel(
    const __hip_bfloat16* __restrict__ xh, const __hip_bfloat16* __restrict__ kk,
    const float* __restrict__ wTe1, const float* __restrict__ eb1,
    const float* __restrict__ wTe2, const float* __restrict__ eb2,
    const float* __restrict__ wT3, const float* __restrict__ eb3,
    const float* __restrict__ gate, const float* __restrict__ out2map,
    const float* __restrict__ x, float* __restrict__ out)
{
    const int b = blockIdx.z, h = blockIdx.y, w0 = blockIdx.x * 32;
    const int t = threadIdx.x;
    const int ph = t & 1, cb = t >> 1;  // cb 0..63
    __shared__ float sxh[8][3][36], skk[8][3][36];
    __shared__ float sprod[128][36];
    float out_acc[2][16];
#pragma unroll
    for (int q = 0; q < 2; q++)
#pragma unroll
        for (int p = 0; p < 16; p++) out_acc[q][p] = 0.f;

    const size_t bchw = (size_t)b * CC_ * HH * WW;

    for (int e = 0; e < 3; e++) {
        float we = gate[b * 3 + e];
        if (we == 0.f) continue;   // uniform across block

        float acc_a[2][16], acc_b[2][16];
#pragma unroll
        for (int q = 0; q < 2; q++)
#pragma unroll
            for (int p = 0; p < 16; p++) { acc_a[q][p] = 0.f; acc_b[q][p] = 0.f; }

        for (int c0 = 0; c0 < 128; c0 += 8) {
            __syncthreads();
            for (int i = t; i < 816; i += 128) {
                int col = i % 34;
                int rr = (i / 34) % 3;
                int cc = i / 102;
                int gh = h + rr - 1, gw2 = w0 + col - 1;
                float vx = 0.f, vk = 0.f;
                if ((unsigned)gh < 128u && (unsigned)gw2 < 128u) {
                    size_t idx = bchw + ((size_t)(c0 + cc) * 128 + gh) * 128 + gw2;
                    vx = __bfloat162float(xh[idx]);
                    vk = __bfloat162float(kk[idx]);
                }
                sxh[cc][rr][col] = vx;
                skk[cc][rr][col] = vk;
            }
            __syncthreads();
#pragma unroll 1
            for (int cc = 0; cc < 8; cc++) {
                const float* w1p = wTe1 + (size_t)((e * 128 + c0 + cc) * 9) * 128 + cb;
                const float* w2p = wTe2 + (size_t)((e * 128 + c0 + cc) * 9) * 128 + cb;
#pragma unroll
                for (int r = 0; r < 3; r++) {
                    float xvh[18], xvk[18];
#pragma unroll
                    for (int j = 0; j < 18; j++) {
                        xvh[j] = sxh[cc][r][ph * 16 + j];
                        xvk[j] = skk[cc][r][ph * 16 + j];
                    }
#pragma unroll
                    for (int j = 0; j < 3; j++) {
                        int tap = r * 3 + j;
                        float a0 = w1p[tap * 128], a1 = w1p[tap * 128 + 64];
                        float b0 = w2p[tap * 128], b1 = w2p[tap * 128 + 64];
#pragma unroll
                        for (int p = 0; p < 16; p++) {
                            acc_a[0][p] += xvh[p + j] * a0;
                            acc_a[1][p] += xvh[p + j] * a1;
                            acc_b[0][p] += xvk[p + j] * b0;
                            acc_b[1][p] += xvk[p + j] * b1;
                        }
                    }
                }
            }
        }

        __syncthreads();
#pragma unroll
        for (int q = 0; q < 2; q++) {
            int c = cb + q * 64;
            float b1v = eb1[e * 128 + c], b2v = eb2[e * 128 + c];
#pragma unroll
            for (int p = 0; p < 16; p++)
                sprod[c][ph * 16 + p] = (acc_a[q][p] + b1v) * (acc_b[q][p] + b2v);
        }
        __syncthreads();

        // 1x1 conv over channels from LDS
        float eo[2][16];
#pragma unroll
        for (int q = 0; q < 2; q++)
#pragma unroll
            for (int p = 0; p < 16; p++) eo[q][p] = 0.f;
#pragma unroll 1
        for (int cc = 0; cc < 128; cc++) {
            float w30 = wT3[(size_t)(e * 128 + cc) * 128 + cb];
            float w31 = wT3[(size_t)(e * 128 + cc) * 128 + cb + 64];
#pragma unroll
            for (int p = 0; p < 16; p++) {
                float pv = sprod[cc][ph * 16 + p];
                eo[0][p] += pv * w30;
                eo[1][p] += pv * w31;
            }
        }
#pragma unroll
        for (int q = 0; q < 2; q++) {
            float b3v = eb3[e * 128 + cb + q * 64];
#pragma unroll
            for (int p = 0; p < 16; p++)
                out_acc[q][p] += we * (eo[q][p] + b3v);
        }
    }

    // final: out = xh + sum_e w_e*eo_e + out2map[c][region] + x
    const int wbase = w0 + ph * 16;
    const int rcl = (h == 0) ? 0 : ((h == 127) ? 2 : 1);
#pragma unroll
    for (int q = 0; q < 2; q++) {
        int c = cb + q * 64;
        size_t base = bchw + ((size_t)c * 128 + h) * 128 + wbase;
        const float* o2 = out2map + c * 9 + rcl * 3;
#pragma unroll
        for (int p = 0; p < 16; p++) {
            int w = wbase + p;
            int ccl = (w == 0) ? 0 : ((w == 127) ? 2 : 1);
            out[base + p] = __bfloat162float(xh[base + p]) + out_acc[q][p]
                          + o2[ccl] + x[base + p];
        }
    }
}

// ---------------------------------------------------------------------------
extern "C" void kernel_launch(void* const* d_in, const int* in_sizes, int n_in,
                              void* d_out, int out_size, void* d_ws, size_t ws_size,
                              hipStream_t stream)
{
    const float* x      = (const float*)d_in[0];
    const float* a_c1w  = (const float*)d_in[1];
    const float* a_c1b  = (const float*)d_in[2];
    const float* a_gw   = (const float*)d_in[3];
    const float* a_ew1  = (const float*)d_in[4];
    const float* a_eb1  = (const float*)d_in[5];
    const float* a_ew2  = (const float*)d_in[6];
    const float* a_eb2  = (const float*)d_in[7];
    const float* a_ew3  = (const float*)d_in[8];
    const float* a_eb3  = (const float*)d_in[9];
    const float* b_c1w  = (const float*)d_in[10]; (void)b_c1w; // unused: conv(0)=bias
    const float* b_c1b  = (const float*)d_in[11];
    const float* b_gw   = (const float*)d_in[12];
    const float* b_ew1  = (const float*)d_in[13];
    const float* b_eb1  = (const float*)d_in[14];
    const float* b_ew2  = (const float*)d_in[15];
    const float* b_eb2  = (const float*)d_in[16];
    const float* b_ew3  = (const float*)d_in[17];
    const float* b_eb3  = (const float*)d_in[18];
    float* out = (float*)d_out;

    char* ws = (char*)d_ws;
    __hip_bfloat16* xh = (__hip_bfloat16*)(ws);
    __hip_bfloat16* kk = (__hip_bfloat16*)(ws + 33554432);
    float* wT1     = (float*)(ws + 67108864);
    float* wTe1    = (float*)(ws + 68288512);
    float* wTe2    = (float*)(ws + 70057984);
    float* wT3     = (float*)(ws + 71827456);
    float* meansum = (float*)(ws + 72024064);
    float* gate    = (float*)(ws + 72028160);
    float* out2map = (float*)(ws + 72028672);

    hipMemsetAsync(meansum, 0, 1024 * sizeof(float), stream);

    t1_kernel<<<(256 * 128 * 9 + 255) / 256, 256, 0, stream>>>(a_c1w, wT1);
    te_kernel<<<(3 * 128 * 128 * 9 + 255) / 256, 256, 0, stream>>>(a_ew1, wTe1);
    te_kernel<<<(3 * 128 * 128 * 9 + 255) / 256, 256, 0, stream>>>(a_ew2, wTe2);
    t3_kernel<<<(3 * 128 * 128 + 255) / 256, 256, 0, stream>>>(a_ew3, wT3);

    conv1_kernel<<<dim3(4, 128, 8), 128, 0, stream>>>(x, wT1, a_c1b, xh, kk, meansum);
    gate_kernel<<<1, 64, 0, stream>>>(meansum, a_gw, gate);
    out2_kernel<<<1, 128, 0, stream>>>(b_c1b, b_gw, b_ew1, b_eb1, b_ew2, b_eb2,
                                       b_ew3, b_eb3, out2map);
    expert_kernel<<<dim3(4, 128, 8), 128, 0, stream>>>(
        xh, kk, wTe1, a_eb1, wTe2, a_eb2, wT3, a_eb3, gate, out2map, x, out);
}

// Round 2
// 834.815 us; speedup vs baseline: 4.8576x; 4.8576x over previous
//
#include <hip/hip_runtime.h>
#include <hip/hip_bf16.h>

#define B_ 8
#define C_ 128
#define H_ 128
#define W_ 128

typedef __bf16 bf16;
typedef __bf16 bf16x8 __attribute__((ext_vector_type(8)));
typedef __bf16 bf16x4 __attribute__((ext_vector_type(4)));
typedef float f32x4 __attribute__((ext_vector_type(4)));

// global -> LDS direct copy, 16B per lane; LDS dest is wave-uniform base + lane*16
#define GLD_LDS16(gsrc, ldsdst)                                                              \
    __builtin_amdgcn_global_load_lds((const __attribute__((address_space(1))) void*)(gsrc),  \
                                     (__attribute__((address_space(3))) void*)(ldsdst),      \
                                     16, 0, 0)

// ---------------------------------------------------------------------------
// Weight prep: bf16 + transpose so A-fragment loads are 16B contiguous in cc.
// ---------------------------------------------------------------------------
__global__ void wprep1_kernel(const float* __restrict__ w, bf16* __restrict__ o) {
    // a_c1w [256co][128cc][9tap] -> [9tap][256co][128cc] bf16
    int i = blockIdx.x * 256 + threadIdx.x;
    if (i >= 256 * 128 * 9) return;
    int tap = i % 9, cc = (i / 9) % 128, co = i / (9 * 128);
    o[(tap * 256 + co) * 128 + cc] = (bf16)w[i];
}

__global__ void wprepE_kernel(const float* __restrict__ w, bf16* __restrict__ o) {
    // ew [3][128co][128cc][9] -> [3][9][128co][128cc] bf16
    int i = blockIdx.x * 256 + threadIdx.x;
    if (i >= 3 * 128 * 128 * 9) return;
    int tap = i % 9, cc = (i / 9) % 128, co = (i / (9 * 128)) % 128, e = i / (9 * 128 * 128);
    o[(((e * 9 + tap) * 128 + co) * 128) + cc] = (bf16)w[i];
}

__global__ void wprep3_kernel(const float* __restrict__ w, bf16* __restrict__ o) {
    // ew3 [3][128co][128cc] -> same layout bf16
    int i = blockIdx.x * 256 + threadIdx.x;
    if (i >= 3 * 128 * 128) return;
    o[i] = (bf16)w[i];
}

// ---------------------------------------------------------------------------
// |x| NCHW fp32 -> NHWC bf16 (LDS transpose, coalesced both sides)
// ---------------------------------------------------------------------------
__global__ __launch_bounds__(256) void xpose_kernel(const float* __restrict__ x,
                                                    bf16* __restrict__ xa)
{
    const int cblk = blockIdx.x, h = blockIdx.y, b = blockIdx.z;
    const int t = threadIdx.x;
    __shared__ float sx[32][133];
    for (int i = t; i < 32 * 128; i += 256) {
        int c = i >> 7, w = i & 127;
        sx[c][w] = fabsf(x[((size_t)(b * C_ + cblk * 32 + c) * H_ + h) * W_ + w]);
    }
    __syncthreads();
    for (int g = t; g < 512; g += 256) {
        int w = g >> 2, slot = g & 3;
        bf16x8 v;
#pragma unroll
        for (int j = 0; j < 8; j++) v[j] = (bf16)sx[slot * 8 + j][w];
        *(bf16x8*)&xa[((size_t)(b * H_ + h) * W_ + w) * C_ + cblk * 32 + slot * 8] = v;
    }
}

// ---------------------------------------------------------------------------
// Staging helper semantics (used by conv1/expert):
// LDS tile logical [3 rows][130 w][32 cc] bf16, stored as granules
//   g = row*520 + w*4 + slot_phys, slot_phys = slot ^ ((w>>1)&3), 16B each.
// Tail-padded to 1600 granules (25600 B).
// ---------------------------------------------------------------------------

// K1: y = conv3x3(|x|) + bias -> xh/kk (NHWC bf16) + per-(b,co) sums.
// block 512 (8 waves); tile 128 px (one row) x 256 co; wave = 64co x 64px.
__global__ __launch_bounds__(512) void conv1_kernel(
    const bf16* __restrict__ xa, const bf16* __restrict__ wT1,
    const float* __restrict__ bias,
    bf16* __restrict__ xh, bf16* __restrict__ kk,
    float* __restrict__ meansum, const bf16* __restrict__ zbuf)
{
    const int h = blockIdx.x, b = blockIdx.y;
    const int t = threadIdx.x, lane = t & 63, ww = t >> 6;
    const int l15 = lane & 15, l4 = lane >> 4;
    const int co0 = (ww >> 1) * 64, px0 = (ww & 1) * 64;
    __shared__ char sm[25600];

    f32x4 acc[4][4];
#pragma unroll
    for (int mf = 0; mf < 4; mf++)
#pragma unroll
        for (int nf = 0; nf < 4; nf++) acc[mf][nf] = (f32x4){0.f, 0.f, 0.f, 0.f};

    for (int cb = 0; cb < 4; cb++) {
        __syncthreads();
        for (int g0 = ww * 64; g0 < 1560; g0 += 512) {
            int g = g0 + lane;
            int row = g / 520, rem = g - row * 520;
            int w = rem >> 2, sp = rem & 3;
            int slot = sp ^ ((w >> 1) & 3);
            int hh = h + row - 1, gw = w - 1;
            const bf16* src = zbuf;
            if (g < 1560 && (unsigned)hh < 128u && (unsigned)gw < 128u)
                src = xa + ((size_t)(b * H_ + hh) * W_ + gw) * C_ + cb * 32 + slot * 8;
            GLD_LDS16(src, sm + g0 * 16);
        }
        asm volatile("s_waitcnt vmcnt(0)" ::: "memory");
        __syncthreads();

#pragma unroll 1
        for (int dy = 0; dy < 3; dy++) {
#pragma unroll
            for (int dx = 0; dx < 3; dx++) {
                const int tap = dy * 3 + dx;
                bf16x8 af[4];
#pragma unroll
                for (int mf = 0; mf < 4; mf++)
                    af[mf] = *(const bf16x8*)&wT1[(size_t)(tap * 256 + co0 + mf * 16 + l15) * 128 + cb * 32 + l4 * 8];
                bf16x8 bv[4];
#pragma unroll
                for (int nf = 0; nf < 4; nf++) {
                    int wl = px0 + nf * 16 + l15 + dx;
                    int byt = (dy * 520 + wl * 4 + (l4 ^ ((wl >> 1) & 3))) * 16;
                    bv[nf] = *(const bf16x8*)(sm + byt);
                }
#pragma unroll
                for (int mf = 0; mf < 4; mf++)
#pragma unroll
                    for (int nf = 0; nf < 4; nf++)
                        acc[mf][nf] = __builtin_amdgcn_mfma_f32_16x16x32_bf16(af[mf], bv[nf], acc[mf][nf], 0, 0, 0);
            }
        }
    }

    // epilogue: bias, NHWC bf16 store, gating sums
    float bvv[4][4];
#pragma unroll
    for (int mf = 0; mf < 4; mf++)
#pragma unroll
        for (int r = 0; r < 4; r++) bvv[mf][r] = bias[co0 + mf * 16 + 4 * l4 + r];

    bf16* dst = (co0 < 128) ? xh : kk;
    const int cod = co0 & 127;
#pragma unroll
    for (int mf = 0; mf < 4; mf++) {
#pragma unroll
        for (int nf = 0; nf < 4; nf++) {
            int px = px0 + nf * 16 + l15;
            bf16x4 v;
#pragma unroll
            for (int r = 0; r < 4; r++) v[r] = (bf16)(acc[mf][nf][r] + bvv[mf][r]);
            *(bf16x4*)&dst[((size_t)(b * H_ + h) * W_ + px) * C_ + cod + mf * 16 + 4 * l4] = v;
        }
        if (co0 < 128) {
#pragma unroll
            for (int r = 0; r < 4; r++) {
                float s = 4.f * bvv[mf][r];
#pragma unroll
                for (int nf = 0; nf < 4; nf++) s += acc[mf][nf][r];
                s += __shfl_xor(s, 1, 64);
                s += __shfl_xor(s, 2, 64);
                s += __shfl_xor(s, 4, 64);
                s += __shfl_xor(s, 8, 64);
                if (l15 == 0)
                    atomicAdd(&meansum[b * 128 + co0 + mf * 16 + 4 * l4 + r], s);
            }
        }
    }
}

// ---------------------------------------------------------------------------
// K2: gating (top-2 of 3; drop argmin, ties drop larger index)
// ---------------------------------------------------------------------------
__global__ void gate_kernel(const float* __restrict__ meansum,
                            const float* __restrict__ gw,
                            float* __restrict__ gate)
{
    int b = threadIdx.x;
    if (b >= 8) return;
    float l[3];
    for (int e = 0; e < 3; e++) {
        float s = 0.f;
        for (int c = 0; c < 128; c++) s += meansum[b * 128 + c] * gw[e * 128 + c];
        l[e] = s * (1.0f / 16384.0f);
    }
    float m = fmaxf(l[0], fmaxf(l[1], l[2]));
    float p0 = expf(l[0] - m), p1 = expf(l[1] - m), p2 = expf(l[2] - m);
    float s = p0 + p1 + p2;
    float w[3] = { p0 / s, p1 / s, p2 / s };
    int dm = 0;
    if (w[1] <= w[0]) dm = 1;
    if (w[2] <= w[dm]) dm = 2;
    for (int e = 0; e < 3; e++) gate[b * 3 + e] = (e == dm) ? 0.f : w[e];
}

// ---------------------------------------------------------------------------
// K3: fem_b on zero input -> batch-independent [C][9-region] map (fp32)
// ---------------------------------------------------------------------------
__global__ __launch_bounds__(128) void out2_kernel(
    const float* __restrict__ c1b, const float* __restrict__ gw,
    const float* __restrict__ ew1, const float* __restrict__ eb1,
    const float* __restrict__ ew2, const float* __restrict__ eb2,
    const float* __restrict__ ew3, const float* __restrict__ eb3,
    float* __restrict__ out2map)
{
    __shared__ float sxh[128], skk[128];
    __shared__ float sprod[3][128][9];
    int c = threadIdx.x;
    sxh[c] = c1b[c];
    skk[c] = c1b[128 + c];
    __syncthreads();

    for (int e = 0; e < 3; e++) {
        float A[9], Bv[9];
#pragma unroll
        for (int tp = 0; tp < 9; tp++) { A[tp] = 0.f; Bv[tp] = 0.f; }
        for (int cc = 0; cc < 128; cc++) {
            float xv = sxh[cc], kv = skk[cc];
            const float* w1 = ew1 + ((size_t)(e * 128 + c) * 128 + cc) * 9;
            const float* w2 = ew2 + ((size_t)(e * 128 + c) * 128 + cc) * 9;
#pragma unroll
            for (int tp = 0; tp < 9; tp++) {
                A[tp] += xv * w1[tp];
                Bv[tp] += kv * w2[tp];
            }
        }
        float b1 = eb1[e * 128 + c], b2 = eb2[e * 128 + c];
        for (int rcl = 0; rcl < 3; rcl++) {
            for (int ccl = 0; ccl < 3; ccl++) {
                float av = b1, bv = b2;
#pragma unroll
                for (int i = 0; i < 3; i++) {
#pragma unroll
                    for (int j = 0; j < 3; j++) {
                        bool iok = (rcl == 1) || (rcl == 0 && i >= 1) || (rcl == 2 && i <= 1);
                        bool jok = (ccl == 1) || (ccl == 0 && j >= 1) || (ccl == 2 && j <= 1);
                        if (iok && jok) { av += A[i * 3 + j]; bv += Bv[i * 3 + j]; }
                    }
                }
                sprod[e][c][rcl * 3 + ccl] = av * bv;
            }
        }
    }
    __syncthreads();

    float eo[3][9];
    for (int e = 0; e < 3; e++) {
        float b3 = eb3[e * 128 + c];
#pragma unroll
        for (int r = 0; r < 9; r++) eo[e][r] = b3;
        for (int cc = 0; cc < 128; cc++) {
            float wv = ew3[(size_t)(e * 128 + c) * 128 + cc];
#pragma unroll
            for (int r = 0; r < 9; r++) eo[e][r] += wv * sprod[e][cc][r];
        }
    }

    float l[3];
    for (int e = 0; e < 3; e++) {
        float s = 0.f;
        for (int cc = 0; cc < 128; cc++) s += sxh[cc] * gw[e * 128 + cc];
        l[e] = s;
    }
    float m = fmaxf(l[0], fmaxf(l[1], l[2]));
    float p0 = expf(l[0] - m), p1 = expf(l[1] - m), p2 = expf(l[2] - m);
    float ssum = p0 + p1 + p2;
    float wv[3] = { p0 / ssum, p1 / ssum, p2 / ssum };
    int dm = 0;
    if (wv[1] <= wv[0]) dm = 1;
    if (wv[2] <= wv[dm]) dm = 2;
    wv[dm] = 0.f;

    for (int r = 0; r < 9; r++) {
        float o = sxh[c];
        for (int e = 0; e < 3; e++) o += wv[e] * eo[e][r];
        out2map[c * 9 + r] = o;
    }
}

// ---------------------------------------------------------------------------
// K4: per-batch top-2 experts, MFMA implicit GEMM.
// block 512 (8 waves); tile 128 px (one row) x 128 co; wave = 32co x 64px.
// P = (conv_a+b1)*(conv_b+b2) staged bf16 in LDS (aliases staging buffers),
// then 1x1 GEMM; out = xh + sum we*eo + out2map + x.
// ---------------------------------------------------------------------------
__global__ __launch_bounds__(512) void expert_kernel(
    const bf16* __restrict__ xh, const bf16* __restrict__ kk,
    const bf16* __restrict__ we1, const float* __restrict__ eb1,
    const bf16* __restrict__ we2, const float* __restrict__ eb2,
    const bf16* __restrict__ w3, const float* __restrict__ eb3,
    const float* __restrict__ gate, const float* __restrict__ o2map,
    const float* __restrict__ x, float* __restrict__ out,
    const bf16* __restrict__ zbuf)
{
    const int h = blockIdx.x, b = blockIdx.y;
    const int t = threadIdx.x, lane = t & 63, ww = t >> 6;
    const int l15 = lane & 15, l4 = lane >> 4;
    const int co0 = (ww >> 1) * 32, px0 = (ww & 1) * 64;
    __shared__ char sm[51200];
    char* sxh = sm;
    char* skk = sm + 25600;

    f32x4 oacc[2][4];
#pragma unroll
    for (int mf = 0; mf < 2; mf++)
#pragma unroll
        for (int nf = 0; nf < 4; nf++) oacc[mf][nf] = (f32x4){0.f, 0.f, 0.f, 0.f};

    for (int e = 0; e < 3; e++) {
        const float we = gate[b * 3 + e];
        if (we == 0.f) continue;   // uniform across block

        f32x4 aa[2][4], ab[2][4];
#pragma unroll
        for (int mf = 0; mf < 2; mf++)
#pragma unroll
            for (int nf = 0; nf < 4; nf++) {
                aa[mf][nf] = (f32x4){0.f, 0.f, 0.f, 0.f};
                ab[mf][nf] = (f32x4){0.f, 0.f, 0.f, 0.f};
            }

        for (int cb = 0; cb < 4; cb++) {
            __syncthreads();
            for (int g0 = ww * 64; g0 < 1560; g0 += 512) {
                int g = g0 + lane;
                int row = g / 520, rem = g - row * 520;
                int w = rem >> 2, sp = rem & 3;
                int slot = sp ^ ((w >> 1) & 3);
                int hh = h + row - 1, gw = w - 1;
                const bf16* sx = zbuf;
                const bf16* sk = zbuf;
                if (g < 1560 && (unsigned)hh < 128u && (unsigned)gw < 128u) {
                    size_t off = ((size_t)(b * H_ + hh) * W_ + gw) * C_ + cb * 32 + slot * 8;
                    sx = xh + off;
                    sk = kk + off;
                }
                GLD_LDS16(sx, sxh + g0 * 16);
                GLD_LDS16(sk, skk + g0 * 16);
            }
            asm volatile("s_waitcnt vmcnt(0)" ::: "memory");
            __syncthreads();

#pragma unroll 1
            for (int dy = 0; dy < 3; dy++) {
#pragma unroll
                for (int dx = 0; dx < 3; dx++) {
                    const int tap = dy * 3 + dx;
                    bf16x8 a1[2], a2[2];
#pragma unroll
                    for (int mf = 0; mf < 2; mf++) {
                        size_t wi = (size_t)((e * 9 + tap) * 128 + co0 + mf * 16 + l15) * 128 + cb * 32 + l4 * 8;
                        a1[mf] = *(const bf16x8*)&we1[wi];
                        a2[mf] = *(const bf16x8*)&we2[wi];
                    }
#pragma unroll
                    for (int nf = 0; nf < 4; nf++) {
                        int wl = px0 + nf * 16 + l15 + dx;
                        int byt = (dy * 520 + wl * 4 + (l4 ^ ((wl >> 1) & 3))) * 16;
                        bf16x8 bx = *(const bf16x8*)(sxh + byt);
                        bf16x8 bk = *(const bf16x8*)(skk + byt);
#pragma unroll
                        for (int mf = 0; mf < 2; mf++) {
                            aa[mf][nf] = __builtin_amdgcn_mfma_f32_16x16x32_bf16(a1[mf], bx, aa[mf][nf], 0, 0, 0);
                            ab[mf][nf] = __builtin_amdgcn_mfma_f32_16x16x32_bf16(a2[mf], bk, ab[mf][nf], 0, 0, 0);
                        }
                    }
                }
            }
        }
        __syncthreads();   // staging reads complete block-wide before P overwrite

        // P = (a + b1)*(bb + b2) -> LDS [128px][128cc] bf16, slot ^= (px&15)
        float b1v[2][4], b2v[2][4];
#pragma unroll
        for (int mf = 0; mf < 2; mf++)
#pragma unroll
            for (int r = 0; r < 4; r++) {
                int c = co0 + mf * 16 + 4 * l4 + r;
                b1v[mf][r] = eb1[e * 128 + c];
                b2v[mf][r] = eb2[e * 128 + c];
            }
#pragma unroll
        for (int mf = 0; mf < 2; mf++)
#pragma unroll
            for (int nf = 0; nf < 4; nf++) {
                int px = px0 + nf * 16 + l15;
                int ccb = co0 + mf * 16 + 4 * l4;
                bf16x4 pv;
#pragma unroll
                for (int r = 0; r < 4; r++)
                    pv[r] = (bf16)((aa[mf][nf][r] + b1v[mf][r]) * (ab[mf][nf][r] + b2v[mf][r]));
                int byt = px * 256 + (((ccb >> 3) ^ (px & 15)) * 16) + (ccb & 7) * 2;
                *(bf16x4*)(sm + byt) = pv;
            }
        __syncthreads();

        // 1x1 conv GEMM over K=128
        f32x4 eo[2][4];
#pragma unroll
        for (int mf = 0; mf < 2; mf++)
#pragma unroll
            for (int nf = 0; nf < 4; nf++) eo[mf][nf] = (f32x4){0.f, 0.f, 0.f, 0.f};
#pragma unroll 1
        for (int ks = 0; ks < 4; ks++) {
            bf16x8 a3[2];
#pragma unroll
            for (int mf = 0; mf < 2; mf++)
                a3[mf] = *(const bf16x8*)&w3[(size_t)(e * 128 + co0 + mf * 16 + l15) * 128 + ks * 32 + l4 * 8];
#pragma unroll
            for (int nf = 0; nf < 4; nf++) {
                int px = px0 + nf * 16 + l15;
                int slot = ks * 4 + l4;
                int byt = px * 256 + ((slot ^ (px & 15)) * 16);
                bf16x8 bp = *(const bf16x8*)(sm + byt);
#pragma unroll
                for (int mf = 0; mf < 2; mf++)
                    eo[mf][nf] = __builtin_amdgcn_mfma_f32_16x16x32_bf16(a3[mf], bp, eo[mf][nf], 0, 0, 0);
            }
        }
#pragma unroll
        for (int mf = 0; mf < 2; mf++)
#pragma unroll
            for (int nf = 0; nf < 4; nf++) {
#pragma unroll
                for (int r = 0; r < 4; r++) {
                    float b3v = eb3[e * 128 + co0 + mf * 16 + 4 * l4 + r];
                    oacc[mf][nf][r] += we * (eo[mf][nf][r] + b3v);
                }
            }
        __syncthreads();   // P consumed before next expert restages
    }

    // epilogue: out = xh + sum we*eo + out2map[c][region] + x
    const int rcl = (h == 0) ? 0 : ((h == 127) ? 2 : 1);
#pragma unroll
    for (int mf = 0; mf < 2; mf++)
#pragma unroll
        for (int nf = 0; nf < 4; nf++) {
            int px = px0 + nf * 16 + l15;
            int cbase = co0 + mf * 16 + 4 * l4;
            bf16x4 xv = *(const bf16x4*)&xh[((size_t)(b * H_ + h) * W_ + px) * C_ + cbase];
            int ccl = (px == 0) ? 0 : ((px == 127) ? 2 : 1);
#pragma unroll
            for (int r = 0; r < 4; r++) {
                int c = cbase + r;
                size_t gi = ((size_t)(b * C_ + c) * H_ + h) * W_ + px;
                out[gi] = (float)xv[r] + oacc[mf][nf][r] + o2map[c * 9 + rcl * 3 + ccl] + x[gi];
            }
        }
}

// ---------------------------------------------------------------------------
extern "C" void kernel_launch(void* const* d_in, const int* in_sizes, int n_in,
                              void* d_out, int out_size, void* d_ws, size_t ws_size,
                              hipStream_t stream)
{
    const float* x      = (const float*)d_in[0];
    const float* a_c1w  = (const float*)d_in[1];
    const float* a_c1b  = (const float*)d_in[2];
    const float* a_gw   = (const float*)d_in[3];
    const float* a_ew1  = (const float*)d_in[4];
    const float* a_eb1  = (const float*)d_in[5];
    const float* a_ew2  = (const float*)d_in[6];
    const float* a_eb2  = (const float*)d_in[7];
    const float* a_ew3  = (const float*)d_in[8];
    const float* a_eb3  = (const float*)d_in[9];
    const float* b_c1b  = (const float*)d_in[11];
    const float* b_gw   = (const float*)d_in[12];
    const float* b_ew1  = (const float*)d_in[13];
    const float* b_eb1  = (const float*)d_in[14];
    const float* b_ew2  = (const float*)d_in[15];
    const float* b_eb2  = (const float*)d_in[16];
    const float* b_ew3  = (const float*)d_in[17];
    const float* b_eb3  = (const float*)d_in[18];
    float* out = (float*)d_out;

    char* ws = (char*)d_ws;
    bf16*  xh      = (bf16*)(ws);                      // 33554432 B
    bf16*  kk      = (bf16*)(ws + 33554432);           // 33554432 B
    bf16*  wT1     = (bf16*)(ws + 67108864);           // 589824 B
    bf16*  wTe1    = (bf16*)(ws + 67698688);           // 884736 B
    bf16*  wTe2    = (bf16*)(ws + 68583424);           // 884736 B
    bf16*  wT3     = (bf16*)(ws + 69468160);           // 98304 B
    float* meansum = (float*)(ws + 69566464);          // 4096 B
    float* gate    = (float*)(ws + 69570560);          // 128 B
    float* o2map   = (float*)(ws + 69570688);          // 4608 B
    bf16*  zbuf    = (bf16*)(ws + 69575296);           // 256 B

    // |x| NHWC bf16 scratch lives in d_out (written last by expert_kernel)
    bf16* xa = (bf16*)d_out;

    hipMemsetAsync(ws + 69566464, 0, 4096, stream);        // meansum
    hipMemsetAsync(ws + 69575296, 0, 256, stream);         // zero buffer

    wprep1_kernel<<<(256 * 128 * 9 + 255) / 256, 256, 0, stream>>>(a_c1w, wT1);
    wprepE_kernel<<<(3 * 128 * 128 * 9 + 255) / 256, 256, 0, stream>>>(a_ew1, wTe1);
    wprepE_kernel<<<(3 * 128 * 128 * 9 + 255) / 256, 256, 0, stream>>>(a_ew2, wTe2);
    wprep3_kernel<<<(3 * 128 * 128 + 255) / 256, 256, 0, stream>>>(a_ew3, wT3);

    xpose_kernel<<<dim3(4, 128, 8), 256, 0, stream>>>(x, xa);

    conv1_kernel<<<dim3(128, 8), 512, 0, stream>>>(xa, wT1, a_c1b, xh, kk, meansum, zbuf);

    gate_kernel<<<1, 64, 0, stream>>>(meansum, a_gw, gate);
    out2_kernel<<<1, 128, 0, stream>>>(b_c1b, b_gw, b_ew1, b_eb1, b_ew2, b_eb2,
                                       b_ew3, b_eb3, o2map);

    expert_kernel<<<dim3(128, 8), 512, 0, stream>>>(
        xh, kk, wTe1, a_eb1, wTe2, a_eb2, wT3, a_eb3, gate, o2map, x, out, zbuf);
}

// Round 3
// 708.385 us; speedup vs baseline: 5.7245x; 1.1785x over previous
//
#include <hip/hip_runtime.h>
#include <hip/hip_bf16.h>

#define B_ 8
#define C_ 128
#define H_ 128
#define W_ 128

typedef __bf16 bf16;
typedef __bf16 bf16x8 __attribute__((ext_vector_type(8)));
typedef __bf16 bf16x4 __attribute__((ext_vector_type(4)));
typedef float f32x4 __attribute__((ext_vector_type(4)));

// global -> LDS direct copy, 16B per lane; LDS dest is wave-uniform base + lane*16
#define GLD_LDS16(gsrc, ldsdst)                                                              \
    __builtin_amdgcn_global_load_lds((const __attribute__((address_space(1))) void*)(gsrc),  \
                                     (__attribute__((address_space(3))) void*)(ldsdst),      \
                                     16, 0, 0)

// ---------------------------------------------------------------------------
// Weight prep: bf16 + transpose so A-fragment loads are 16B contiguous in cc.
// ---------------------------------------------------------------------------
__global__ void wprep1_kernel(const float* __restrict__ w, bf16* __restrict__ o) {
    // a_c1w [256co][128cc][9tap] -> [9tap][256co][128cc] bf16
    int i = blockIdx.x * 256 + threadIdx.x;
    if (i >= 256 * 128 * 9) return;
    int tap = i % 9, cc = (i / 9) % 128, co = i / (9 * 128);
    o[(tap * 256 + co) * 128 + cc] = (bf16)w[i];
}

__global__ void wprepE_kernel(const float* __restrict__ w, bf16* __restrict__ o) {
    // ew [3][128co][128cc][9] -> [3][9][128co][128cc] bf16
    int i = blockIdx.x * 256 + threadIdx.x;
    if (i >= 3 * 128 * 128 * 9) return;
    int tap = i % 9, cc = (i / 9) % 128, co = (i / (9 * 128)) % 128, e = i / (9 * 128 * 128);
    o[(((e * 9 + tap) * 128 + co) * 128) + cc] = (bf16)w[i];
}

__global__ void wprep3_kernel(const float* __restrict__ w, bf16* __restrict__ o) {
    // ew3 [3][128co][128cc] -> same layout bf16
    int i = blockIdx.x * 256 + threadIdx.x;
    if (i >= 3 * 128 * 128) return;
    o[i] = (bf16)w[i];
}

// ---------------------------------------------------------------------------
// |x| NCHW fp32 -> NHWC bf16 (LDS transpose, coalesced both sides)
// ---------------------------------------------------------------------------
__global__ __launch_bounds__(256) void xpose_kernel(const float* __restrict__ x,
                                                    bf16* __restrict__ xa)
{
    const int cblk = blockIdx.x, h = blockIdx.y, b = blockIdx.z;
    const int t = threadIdx.x;
    __shared__ float sx[32][133];
    for (int i = t; i < 32 * 128; i += 256) {
        int c = i >> 7, w = i & 127;
        sx[c][w] = fabsf(x[((size_t)(b * C_ + cblk * 32 + c) * H_ + h) * W_ + w]);
    }
    __syncthreads();
    for (int g = t; g < 512; g += 256) {
        int w = g >> 2, slot = g & 3;
        bf16x8 v;
#pragma unroll
        for (int j = 0; j < 8; j++) v[j] = (bf16)sx[slot * 8 + j][w];
        *(bf16x8*)&xa[((size_t)(b * H_ + h) * W_ + w) * C_ + cblk * 32 + slot * 8] = v;
    }
}

// ---------------------------------------------------------------------------
// Staging tile (shared by conv1/expert): logical [4 halo rows][66 w][32 cc],
// granule g = row*272 + w*4 + sp (16B = 8cc), logical slot = sp ^ ((w>>1)&3).
// 1088 granules = 17408 B per tensor. Pad granules (rem>=264) get zeros.
// ---------------------------------------------------------------------------

// K1: y = conv3x3(|x|)+bias -> xh/kk (NHWC bf16) + per-(b,co) sums.
// 512 thr (8 waves), tile 2 rows x 64 px x 256 co; wave = 64co x 64px (1 row).
__global__ __launch_bounds__(512, 4) void conv1_kernel(
    const bf16* __restrict__ xa, const bf16* __restrict__ wT1,
    const float* __restrict__ bias,
    bf16* __restrict__ xh, bf16* __restrict__ kk,
    float* __restrict__ meansum, const bf16* __restrict__ zbuf)
{
    const int bid = blockIdx.x;
    const int b = bid & 7, rp = (bid >> 3) & 63, pxh = bid >> 9;   // XCD: b = bid%8
    const int h0 = rp * 2, w0 = pxh * 64;
    const int t = threadIdx.x, lane = t & 63, ww = t >> 6;
    const int l15 = lane & 15, l4 = lane >> 4;
    const int rowL = ww & 1, co0 = (ww >> 1) * 64;
    __shared__ char sm[17408];

    f32x4 acc[4][4];   // [mf co][nf px]
#pragma unroll
    for (int mf = 0; mf < 4; mf++)
#pragma unroll
        for (int nf = 0; nf < 4; nf++) acc[mf][nf] = (f32x4){0.f, 0.f, 0.f, 0.f};

    for (int cb = 0; cb < 4; cb++) {
        __syncthreads();
        for (int g0 = ww * 64; g0 < 1088; g0 += 512) {
            int g = g0 + lane;
            int row = g / 272, rem = g - row * 272;
            int w = rem >> 2, sp = rem & 3;
            int slot = sp ^ ((w >> 1) & 3);
            int hh = h0 + row - 1, gw = w0 + w - 1;
            const bf16* src = zbuf;
            if (rem < 264 && (unsigned)hh < 128u && (unsigned)gw < 128u)
                src = xa + ((size_t)(b * H_ + hh) * W_ + gw) * C_ + cb * 32 + slot * 8;
            GLD_LDS16(src, sm + g0 * 16);
        }
        asm volatile("s_waitcnt vmcnt(0)" ::: "memory");
        __syncthreads();

#pragma unroll 1
        for (int dy = 0; dy < 3; dy++) {
            const int row_h = rowL + dy;
#pragma unroll
            for (int dx = 0; dx < 3; dx++) {
                const int tap = dy * 3 + dx;
                bf16x8 af[4];
#pragma unroll
                for (int mf = 0; mf < 4; mf++)
                    af[mf] = *(const bf16x8*)&wT1[(size_t)(tap * 256 + co0 + mf * 16 + l15) * 128 + cb * 32 + l4 * 8];
                bf16x8 bv[4];
#pragma unroll
                for (int nf = 0; nf < 4; nf++) {
                    int wl = nf * 16 + l15 + dx;
                    int byt = (row_h * 272 + wl * 4 + (l4 ^ ((wl >> 1) & 3))) * 16;
                    bv[nf] = *(const bf16x8*)(sm + byt);
                }
#pragma unroll
                for (int mf = 0; mf < 4; mf++)
#pragma unroll
                    for (int nf = 0; nf < 4; nf++)
                        acc[mf][nf] = __builtin_amdgcn_mfma_f32_16x16x32_bf16(af[mf], bv[nf], acc[mf][nf], 0, 0, 0);
            }
        }
    }

    // epilogue: bias, NHWC bf16 store, gating sums
    const int hG = h0 + rowL;
    float bvv[4][4];
#pragma unroll
    for (int mf = 0; mf < 4; mf++)
#pragma unroll
        for (int r = 0; r < 4; r++) bvv[mf][r] = bias[co0 + mf * 16 + 4 * l4 + r];

    bf16* dst = (co0 < 128) ? xh : kk;
    const int cod = co0 & 127;
#pragma unroll
    for (int mf = 0; mf < 4; mf++) {
#pragma unroll
        for (int nf = 0; nf < 4; nf++) {
            int w = w0 + nf * 16 + l15;
            bf16x4 v;
#pragma unroll
            for (int r = 0; r < 4; r++) v[r] = (bf16)(acc[mf][nf][r] + bvv[mf][r]);
            *(bf16x4*)&dst[((size_t)(b * H_ + hG) * W_ + w) * C_ + cod + mf * 16 + 4 * l4] = v;
        }
        if (co0 < 128) {
#pragma unroll
            for (int r = 0; r < 4; r++) {
                float s = 4.f * bvv[mf][r];
#pragma unroll
                for (int nf = 0; nf < 4; nf++) s += acc[mf][nf][r];
                s += __shfl_xor(s, 1, 64);
                s += __shfl_xor(s, 2, 64);
                s += __shfl_xor(s, 4, 64);
                s += __shfl_xor(s, 8, 64);
                if (l15 == 0)
                    atomicAdd(&meansum[b * 128 + co0 + mf * 16 + 4 * l4 + r], s);
            }
        }
    }
}

// ---------------------------------------------------------------------------
// K2: gating (top-2 of 3; drop argmin, ties drop larger index)
// ---------------------------------------------------------------------------
__global__ void gate_kernel(const float* __restrict__ meansum,
                            const float* __restrict__ gw,
                            float* __restrict__ gate)
{
    int b = threadIdx.x;
    if (b >= 8) return;
    float l[3];
    for (int e = 0; e < 3; e++) {
        float s = 0.f;
        for (int c = 0; c < 128; c++) s += meansum[b * 128 + c] * gw[e * 128 + c];
        l[e] = s * (1.0f / 16384.0f);
    }
    float m = fmaxf(l[0], fmaxf(l[1], l[2]));
    float p0 = expf(l[0] - m), p1 = expf(l[1] - m), p2 = expf(l[2] - m);
    float s = p0 + p1 + p2;
    float w[3] = { p0 / s, p1 / s, p2 / s };
    int dm = 0;
    if (w[1] <= w[0]) dm = 1;
    if (w[2] <= w[dm]) dm = 2;
    for (int e = 0; e < 3; e++) gate[b * 3 + e] = (e == dm) ? 0.f : w[e];
}

// ---------------------------------------------------------------------------
// K3a/K3b: fem_b on zero input -> batch-independent [C][9-region] map (fp32),
// parallelized (the single-block version serialized ~5 MB of weight reads).
// ---------------------------------------------------------------------------
__global__ __launch_bounds__(128) void out2a_kernel(
    const float* __restrict__ c1b,
    const float* __restrict__ ew1, const float* __restrict__ eb1,
    const float* __restrict__ ew2, const float* __restrict__ eb2,
    float* __restrict__ sprod /* [3][128][9] */)
{
    const int e = blockIdx.x >> 7, c = blockIdx.x & 127;
    const int t = threadIdx.x;   // cc
    float xv = c1b[t], kv = c1b[128 + t];
    const float* w1 = ew1 + ((size_t)(e * 128 + c) * 128 + t) * 9;
    const float* w2 = ew2 + ((size_t)(e * 128 + c) * 128 + t) * 9;
    __shared__ float rA[9][128], rB[9][128];
#pragma unroll
    for (int tp = 0; tp < 9; tp++) { rA[tp][t] = xv * w1[tp]; rB[tp][t] = kv * w2[tp]; }
    __syncthreads();
    for (int s = 64; s > 0; s >>= 1) {
        if (t < s)
#pragma unroll
            for (int tp = 0; tp < 9; tp++) { rA[tp][t] += rA[tp][t + s]; rB[tp][t] += rB[tp][t + s]; }
        __syncthreads();
    }
    if (t < 9) {
        int rcl = t / 3, ccl = t % 3;
        float av = eb1[e * 128 + c], bv = eb2[e * 128 + c];
#pragma unroll
        for (int i = 0; i < 3; i++)
#pragma unroll
            for (int j = 0; j < 3; j++) {
                bool iok = (rcl == 1) || (rcl == 0 && i >= 1) || (rcl == 2 && i <= 1);
                bool jok = (ccl == 1) || (ccl == 0 && j >= 1) || (ccl == 2 && j <= 1);
                if (iok && jok) { av += rA[i * 3 + j][0]; bv += rB[i * 3 + j][0]; }
            }
        sprod[(size_t)(e * 128 + c) * 9 + t] = av * bv;
    }
}

__global__ __launch_bounds__(128) void out2b_kernel(
    const float* __restrict__ c1b, const float* __restrict__ gw,
    const float* __restrict__ sprod, const float* __restrict__ ew3,
    const float* __restrict__ eb3, float* __restrict__ out2map)
{
    const int c = blockIdx.x;
    const int t = threadIdx.x;   // cc
    __shared__ float red[27][128];
#pragma unroll
    for (int e = 0; e < 3; e++) {
        float wv = ew3[(size_t)(e * 128 + c) * 128 + t];
#pragma unroll
        for (int r = 0; r < 9; r++) red[e * 9 + r][t] = wv * sprod[(size_t)(e * 128 + t) * 9 + r];
    }
    __syncthreads();
    for (int s = 64; s > 0; s >>= 1) {
        if (t < s)
#pragma unroll
            for (int q = 0; q < 27; q++) red[q][t] += red[q][t + s];
        __syncthreads();
    }
    __shared__ float lsh[3];
    if (t < 3) {
        float s = 0.f;
        for (int cc = 0; cc < 128; cc++) s += c1b[cc] * gw[t * 128 + cc];
        lsh[t] = s;
    }
    __syncthreads();
    if (t == 0) {
        float l0 = lsh[0], l1 = lsh[1], l2 = lsh[2];
        float m = fmaxf(l0, fmaxf(l1, l2));
        float p0 = expf(l0 - m), p1 = expf(l1 - m), p2 = expf(l2 - m);
        float ssum = p0 + p1 + p2;
        float wv[3] = { p0 / ssum, p1 / ssum, p2 / ssum };
        int dm = 0;
        if (wv[1] <= wv[0]) dm = 1;
        if (wv[2] <= wv[dm]) dm = 2;
        wv[dm] = 0.f;
        for (int r = 0; r < 9; r++) {
            float o = c1b[c];
            for (int e = 0; e < 3; e++)
                o += wv[e] * (red[e * 9 + r][0] + eb3[e * 128 + c]);
            out2map[c * 9 + r] = o;
        }
    }
}

// ---------------------------------------------------------------------------
// K4: per-batch top-2 experts, MFMA implicit GEMM.
// 512 thr (8 waves), tile 2 rows x 64 px x 128 co; wave = 32co x 64px (1 row).
// e0 phase writes out = xh + x + o2map + we0*eo0; e1 phase does out += we1*eo1.
// ---------------------------------------------------------------------------
__global__ __launch_bounds__(512, 4) void expert_kernel(
    const bf16* __restrict__ xhp, const bf16* __restrict__ kkp,
    const bf16* __restrict__ we1, const float* __restrict__ eb1,
    const bf16* __restrict__ we2, const float* __restrict__ eb2,
    const bf16* __restrict__ w3, const float* __restrict__ eb3,
    const float* __restrict__ gate, const float* __restrict__ o2map,
    const float* __restrict__ x, float* __restrict__ out,
    const bf16* __restrict__ zbuf)
{
    const int bid = blockIdx.x;
    const int b = bid & 7, rp = (bid >> 3) & 63, pxh = bid >> 9;   // XCD: b = bid%8
    const int h0 = rp * 2, w0 = pxh * 64;
    const int t = threadIdx.x, lane = t & 63, ww = t >> 6;
    const int l15 = lane & 15, l4 = lane >> 4;
    const int rowL = ww & 1, co0 = (ww >> 1) * 32;
    __shared__ char sm[34816];
    char* sxh = sm;
    char* skk = sm + 17408;

    // the two active experts (gate has exactly one zero)
    float ga0 = gate[b * 3 + 0], ga1 = gate[b * 3 + 1];
    int e0, e1;
    if (ga0 > 0.f) { e0 = 0; e1 = (ga1 > 0.f) ? 1 : 2; }
    else           { e0 = 1; e1 = 2; }

    for (int ei = 0; ei < 2; ei++) {
        const int e = ei ? e1 : e0;
        const float we = gate[b * 3 + e];

        f32x4 aa[2][4], ab[2][4];   // [mf co][nf px]
#pragma unroll
        for (int mf = 0; mf < 2; mf++)
#pragma unroll
            for (int nf = 0; nf < 4; nf++) {
                aa[mf][nf] = (f32x4){0.f, 0.f, 0.f, 0.f};
                ab[mf][nf] = (f32x4){0.f, 0.f, 0.f, 0.f};
            }

        for (int cb = 0; cb < 4; cb++) {
            __syncthreads();
            for (int g0 = ww * 64; g0 < 1088; g0 += 512) {
                int g = g0 + lane;
                int row = g / 272, rem = g - row * 272;
                int w = rem >> 2, sp = rem & 3;
                int slot = sp ^ ((w >> 1) & 3);
                int hh = h0 + row - 1, gw = w0 + w - 1;
                const bf16* sx = zbuf;
                const bf16* sk = zbuf;
                if (rem < 264 && (unsigned)hh < 128u && (unsigned)gw < 128u) {
                    size_t off = ((size_t)(b * H_ + hh) * W_ + gw) * C_ + cb * 32 + slot * 8;
                    sx = xhp + off;
                    sk = kkp + off;
                }
                GLD_LDS16(sx, sxh + g0 * 16);
                GLD_LDS16(sk, skk + g0 * 16);
            }
            asm volatile("s_waitcnt vmcnt(0)" ::: "memory");
            __syncthreads();

#pragma unroll 1
            for (int dy = 0; dy < 3; dy++) {
                const int row_h = rowL + dy;
#pragma unroll
                for (int dx = 0; dx < 3; dx++) {
                    const int tap = dy * 3 + dx;
                    int bofs[4];
#pragma unroll
                    for (int nf = 0; nf < 4; nf++) {
                        int wl = nf * 16 + l15 + dx;
                        bofs[nf] = (row_h * 272 + wl * 4 + (l4 ^ ((wl >> 1) & 3))) * 16;
                    }
                    // conv_a: weights we1, image xh
                    bf16x8 a1[2];
#pragma unroll
                    for (int mf = 0; mf < 2; mf++)
                        a1[mf] = *(const bf16x8*)&we1[(size_t)((e * 9 + tap) * 128 + co0 + mf * 16 + l15) * 128 + cb * 32 + l4 * 8];
#pragma unroll
                    for (int nf = 0; nf < 4; nf++) {
                        bf16x8 bx = *(const bf16x8*)(sxh + bofs[nf]);
#pragma unroll
                        for (int mf = 0; mf < 2; mf++)
                            aa[mf][nf] = __builtin_amdgcn_mfma_f32_16x16x32_bf16(a1[mf], bx, aa[mf][nf], 0, 0, 0);
                    }
                    // conv_b: weights we2, image kk
                    bf16x8 a2[2];
#pragma unroll
                    for (int mf = 0; mf < 2; mf++)
                        a2[mf] = *(const bf16x8*)&we2[(size_t)((e * 9 + tap) * 128 + co0 + mf * 16 + l15) * 128 + cb * 32 + l4 * 8];
#pragma unroll
                    for (int nf = 0; nf < 4; nf++) {
                        bf16x8 bk = *(const bf16x8*)(skk + bofs[nf]);
#pragma unroll
                        for (int mf = 0; mf < 2; mf++)
                            ab[mf][nf] = __builtin_amdgcn_mfma_f32_16x16x32_bf16(a2[mf], bk, ab[mf][nf], 0, 0, 0);
                    }
                }
            }
        }
        __syncthreads();   // staging reads done block-wide before P overwrite

        // P = (a + b1)*(bb + b2) -> LDS [128 px][128 cc] bf16, XOR-swizzled
        // (px local = rowL*64 + w-offset)
#pragma unroll
        for (int mf = 0; mf < 2; mf++) {
            int ccb = co0 + mf * 16 + 4 * l4;
            float b1v[4], b2v[4];
#pragma unroll
            for (int r = 0; r < 4; r++) {
                b1v[r] = eb1[e * 128 + ccb + r];
                b2v[r] = eb2[e * 128 + ccb + r];
            }
#pragma unroll
            for (int nf = 0; nf < 4; nf++) {
                int px = rowL * 64 + nf * 16 + l15;
                bf16x4 pv;
#pragma unroll
                for (int r = 0; r < 4; r++)
                    pv[r] = (bf16)((aa[mf][nf][r] + b1v[r]) * (ab[mf][nf][r] + b2v[r]));
                int byt = px * 256 + (((ccb >> 3) ^ (px & 15)) * 16) + (ccb & 7) * 2;
                *(bf16x4*)(sm + byt) = pv;
            }
        }
        __syncthreads();

        // 1x1 conv GEMM over K=128; wave repartition: 32co x 64px
        const int co0q = (ww >> 1) * 32, px0q = (ww & 1) * 64;
        f32x4 eo[2][4];
#pragma unroll
        for (int mf = 0; mf < 2; mf++)
#pragma unroll
            for (int nf = 0; nf < 4; nf++) eo[mf][nf] = (f32x4){0.f, 0.f, 0.f, 0.f};
#pragma unroll 1
        for (int ks = 0; ks < 4; ks++) {
            bf16x8 a3[2];
#pragma unroll
            for (int mf = 0; mf < 2; mf++)
                a3[mf] = *(const bf16x8*)&w3[(size_t)(e * 128 + co0q + mf * 16 + l15) * 128 + ks * 32 + l4 * 8];
#pragma unroll
            for (int nf = 0; nf < 4; nf++) {
                int px = px0q + nf * 16 + l15;
                int byt = px * 256 + (((ks * 4 + l4) ^ (px & 15)) * 16);
                bf16x8 bp = *(const bf16x8*)(sm + byt);
#pragma unroll
                for (int mf = 0; mf < 2; mf++)
                    eo[mf][nf] = __builtin_amdgcn_mfma_f32_16x16x32_bf16(a3[mf], bp, eo[mf][nf], 0, 0, 0);
            }
        }

        // out write: ei==0 full init, ei==1 accumulate
        const int hGr = h0 + 0;  (void)hGr;
#pragma unroll
        for (int mf = 0; mf < 2; mf++) {
            int cbase = co0q + mf * 16 + 4 * l4;
            float b3v[4];
#pragma unroll
            for (int r = 0; r < 4; r++) b3v[r] = eb3[e * 128 + cbase + r];
#pragma unroll
            for (int nf = 0; nf < 4; nf++) {
                int px = px0q + nf * 16 + l15;
                int h = h0 + (px >> 6), w = w0 + (px & 63);
                if (ei == 0) {
                    bf16x4 xv = *(const bf16x4*)&xhp[((size_t)(b * H_ + h) * W_ + w) * C_ + cbase];
                    int rcl = (h == 0) ? 0 : ((h == 127) ? 2 : 1);
                    int ccl = (w == 0) ? 0 : ((w == 127) ? 2 : 1);
#pragma unroll
                    for (int r = 0; r < 4; r++) {
                        size_t gi = ((size_t)(b * C_ + cbase + r) * H_ + h) * W_ + w;
                        out[gi] = (float)xv[r] + x[gi] + o2map[(cbase + r) * 9 + rcl * 3 + ccl]
                                + we * (eo[mf][nf][r] + b3v[r]);
                    }
                } else {
#pragma unroll
                    for (int r = 0; r < 4; r++) {
                        size_t gi = ((size_t)(b * C_ + cbase + r) * H_ + h) * W_ + w;
                        out[gi] += we * (eo[mf][nf][r] + b3v[r]);
                    }
                }
            }
        }
        __syncthreads();   // P region reused as staging by next expert
    }
}

// ---------------------------------------------------------------------------
extern "C" void kernel_launch(void* const* d_in, const int* in_sizes, int n_in,
                              void* d_out, int out_size, void* d_ws, size_t ws_size,
                              hipStream_t stream)
{
    const float* x      = (const float*)d_in[0];
    const float* a_c1w  = (const float*)d_in[1];
    const float* a_c1b  = (const float*)d_in[2];
    const float* a_gw   = (const float*)d_in[3];
    const float* a_ew1  = (const float*)d_in[4];
    const float* a_eb1  = (const float*)d_in[5];
    const float* a_ew2  = (const float*)d_in[6];
    const float* a_eb2  = (const float*)d_in[7];
    const float* a_ew3  = (const float*)d_in[8];
    const float* a_eb3  = (const float*)d_in[9];
    const float* b_c1b  = (const float*)d_in[11];
    const float* b_gw   = (const float*)d_in[12];
    const float* b_ew1  = (const float*)d_in[13];
    const float* b_eb1  = (const float*)d_in[14];
    const float* b_ew2  = (const float*)d_in[15];
    const float* b_eb2  = (const float*)d_in[16];
    const float* b_ew3  = (const float*)d_in[17];
    const float* b_eb3  = (const float*)d_in[18];
    float* out = (float*)d_out;

    char* ws = (char*)d_ws;
    bf16*  xh      = (bf16*)(ws);                      // 33554432 B
    bf16*  kk      = (bf16*)(ws + 33554432);           // 33554432 B
    bf16*  wT1     = (bf16*)(ws + 67108864);           // 589824 B
    bf16*  wTe1    = (bf16*)(ws + 67698688);           // 884736 B
    bf16*  wTe2    = (bf16*)(ws + 68583424);           // 884736 B
    bf16*  wT3     = (bf16*)(ws + 69468160);           // 98304 B
    float* meansum = (float*)(ws + 69566464);          // 4096 B
    float* gate    = (float*)(ws + 69570560);          // 128 B
    float* o2map   = (float*)(ws + 69570688);          // 4608 B
    bf16*  zbuf    = (bf16*)(ws + 69575296);           // 256 B
    float* sprod   = (float*)(ws + 69575552);          // 3*128*9*4 = 13824 B

    // |x| NHWC bf16 scratch lives in d_out (overwritten last by expert_kernel)
    bf16* xa = (bf16*)d_out;

    hipMemsetAsync(ws + 69566464, 0, 4096, stream);        // meansum
    hipMemsetAsync(ws + 69575296, 0, 256, stream);         // zero buffer

    wprep1_kernel<<<(256 * 128 * 9 + 255) / 256, 256, 0, stream>>>(a_c1w, wT1);
    wprepE_kernel<<<(3 * 128 * 128 * 9 + 255) / 256, 256, 0, stream>>>(a_ew1, wTe1);
    wprepE_kernel<<<(3 * 128 * 128 * 9 + 255) / 256, 256, 0, stream>>>(a_ew2, wTe2);
    wprep3_kernel<<<(3 * 128 * 128 + 255) / 256, 256, 0, stream>>>(a_ew3, wT3);

    xpose_kernel<<<dim3(4, 128, 8), 256, 0, stream>>>(x, xa);

    conv1_kernel<<<1024, 512, 0, stream>>>(xa, wT1, a_c1b, xh, kk, meansum, zbuf);

    gate_kernel<<<1, 64, 0, stream>>>(meansum, a_gw, gate);
    out2a_kernel<<<384, 128, 0, stream>>>(b_c1b, b_ew1, b_eb1, b_ew2, b_eb2, sprod);
    out2b_kernel<<<128, 128, 0, stream>>>(b_c1b, b_gw, sprod, b_ew3, b_eb3, o2map);

    expert_kernel<<<1024, 512, 0, stream>>>(
        xh, kk, wTe1, a_eb1, wTe2, a_eb2, wT3, a_eb3, gate, o2map, x, out, zbuf);
}

// Round 4
// 542.533 us; speedup vs baseline: 7.4745x; 1.3057x over previous
//
#include <hip/hip_runtime.h>
#include <hip/hip_bf16.h>

#define B_ 8
#define C_ 128
#define H_ 128
#define W_ 128

typedef __bf16 bf16;
typedef __bf16 bf16x8 __attribute__((ext_vector_type(8)));
typedef __bf16 bf16x4 __attribute__((ext_vector_type(4)));
typedef float f32x4 __attribute__((ext_vector_type(4)));

#define GLD_LDS16(gsrc, ldsdst)                                                              \
    __builtin_amdgcn_global_load_lds((const __attribute__((address_space(1))) void*)(gsrc),  \
                                     (__attribute__((address_space(3))) void*)(ldsdst),      \
                                     16, 0, 0)

#define WAITVM0 asm volatile("s_waitcnt vmcnt(0)" ::: "memory")
#define WAITVM3 asm volatile("s_waitcnt vmcnt(3)" ::: "memory")

__device__ __forceinline__ void barrier_raw() {
    __builtin_amdgcn_sched_barrier(0);
    __builtin_amdgcn_s_barrier();
    __builtin_amdgcn_sched_barrier(0);
}

// ---------------------------------------------------------------------------
// Weight prep
// ---------------------------------------------------------------------------
__global__ void wprep1_kernel(const float* __restrict__ w, bf16* __restrict__ o) {
    int i = blockIdx.x * 256 + threadIdx.x;
    if (i >= 256 * 128 * 9) return;
    int tap = i % 9, cc = (i / 9) % 128, co = i / (9 * 128);
    o[(tap * 256 + co) * 128 + cc] = (bf16)w[i];
}

__global__ void wprepE_kernel(const float* __restrict__ w, bf16* __restrict__ o) {
    int i = blockIdx.x * 256 + threadIdx.x;
    if (i >= 3 * 128 * 128 * 9) return;
    int tap = i % 9, cc = (i / 9) % 128, co = (i / (9 * 128)) % 128, e = i / (9 * 128 * 128);
    o[(((e * 9 + tap) * 128 + co) * 128) + cc] = (bf16)w[i];
}

__global__ void wprep3_kernel(const float* __restrict__ w, bf16* __restrict__ o) {
    int i = blockIdx.x * 256 + threadIdx.x;
    if (i >= 3 * 128 * 128) return;
    o[i] = (bf16)w[i];
}

// ---------------------------------------------------------------------------
// |x| NCHW fp32 -> NHWC bf16
// ---------------------------------------------------------------------------
__global__ __launch_bounds__(256) void xpose_kernel(const float* __restrict__ x,
                                                    bf16* __restrict__ xa)
{
    const int cblk = blockIdx.x, h = blockIdx.y, b = blockIdx.z;
    const int t = threadIdx.x;
    __shared__ float sx[32][133];
    for (int i = t; i < 32 * 128; i += 256) {
        int c = i >> 7, w = i & 127;
        sx[c][w] = fabsf(x[((size_t)(b * C_ + cblk * 32 + c) * H_ + h) * W_ + w]);
    }
    __syncthreads();
    for (int g = t; g < 512; g += 256) {
        int w = g >> 2, slot = g & 3;
        bf16x8 v;
#pragma unroll
        for (int j = 0; j < 8; j++) v[j] = (bf16)sx[slot * 8 + j][w];
        *(bf16x8*)&xa[((size_t)(b * H_ + h) * W_ + w) * C_ + cblk * 32 + slot * 8] = v;
    }
}

// ---------------------------------------------------------------------------
// Staging tile: logical [4 halo rows][66 w][32 cc] bf16.
// granule g = row*272 + w*4 + sp, slot = sp ^ ((w>>1)&3). 1088 granules.
// Every wave issues EXACTLY 3 global_load_lds per stage (waves 1-7's third
// issue goes to a dump area) so vmcnt immediates are wave-uniform.
// ---------------------------------------------------------------------------
__device__ __forceinline__ void stage_tile(const bf16* __restrict__ base,
    const bf16* __restrict__ zbuf, char* dst, char* dump,
    int t, int ww, int b, int h0, int w0, int cb)
{
#pragma unroll
    for (int k = 0; k < 3; k++) {
        int g = t + k * 512;
        char* d = dst + (size_t)((t & 448) + k * 512) * 16;
        bool real = (k < 2) || (ww == 0);
        if (k == 2 && ww != 0) d = dump;
        const bf16* src = zbuf;
        if (real) {
            int row = g / 272, rem = g - row * 272;
            int w = rem >> 2, sp = rem & 3;
            int slot = sp ^ ((w >> 1) & 3);
            int hh = h0 + row - 1, gw = w0 + w - 1;
            if (rem < 264 && (unsigned)hh < 128u && (unsigned)gw < 128u)
                src = base + ((size_t)(b * H_ + hh) * W_ + gw) * C_ + cb * 32 + slot * 8;
        }
        GLD_LDS16(src, d);
    }
}

// ---------------------------------------------------------------------------
// K1: conv3x3(|x|)+bias -> xh/kk + gating sums. 3-deep rotated staging.
// ---------------------------------------------------------------------------
__global__ __launch_bounds__(512, 2) void conv1_kernel(
    const bf16* __restrict__ xa, const bf16* __restrict__ wT1,
    const float* __restrict__ bias,
    bf16* __restrict__ xh, bf16* __restrict__ kk,
    float* __restrict__ meansum, const bf16* __restrict__ zbuf)
{
    const int bid = blockIdx.x;
    const int b = bid & 7, rp = (bid >> 3) & 63, pxh = bid >> 9;
    const int h0 = rp * 2, w0 = pxh * 64;
    const int t = threadIdx.x, lane = t & 63, ww = t >> 6;
    const int l15 = lane & 15, l4 = lane >> 4;
    const int rowL = ww & 1, co0 = (ww >> 1) * 64;
    __shared__ char sm[53248];
    char* dump = sm + 52224;

    f32x4 acc[4][4];
#pragma unroll
    for (int mf = 0; mf < 4; mf++)
#pragma unroll
        for (int nf = 0; nf < 4; nf++) acc[mf][nf] = (f32x4){0.f, 0.f, 0.f, 0.f};

    stage_tile(xa, zbuf, sm, dump, t, ww, b, h0, w0, 0);
    stage_tile(xa, zbuf, sm + 17408, dump, t, ww, b, h0, w0, 1);

    for (int cb = 0; cb < 4; cb++) {
        if (cb < 3) { WAITVM3; } else { WAITVM0; }
        barrier_raw();
        const char* buf = sm + (size_t)(cb % 3) * 17408;
#pragma unroll 1
        for (int dy = 0; dy < 3; dy++) {
            const int row_h = rowL + dy;
#pragma unroll
            for (int dx = 0; dx < 3; dx++) {
                const int tap = dy * 3 + dx;
                bf16x8 af[4];
#pragma unroll
                for (int mf = 0; mf < 4; mf++)
                    af[mf] = *(const bf16x8*)&wT1[(size_t)(tap * 256 + co0 + mf * 16 + l15) * 128 + cb * 32 + l4 * 8];
                bf16x8 bv[4];
#pragma unroll
                for (int nf = 0; nf < 4; nf++) {
                    int wl = nf * 16 + l15 + dx;
                    int byt = (row_h * 272 + wl * 4 + (l4 ^ ((wl >> 1) & 3))) * 16;
                    bv[nf] = *(const bf16x8*)(buf + byt);
                }
#pragma unroll
                for (int mf = 0; mf < 4; mf++)
#pragma unroll
                    for (int nf = 0; nf < 4; nf++)
                        acc[mf][nf] = __builtin_amdgcn_mfma_f32_16x16x32_bf16(af[mf], bv[nf], acc[mf][nf], 0, 0, 0);
            }
        }
        if (cb < 2)
            stage_tile(xa, zbuf, sm + (size_t)((cb + 2) % 3) * 17408, dump, t, ww, b, h0, w0, cb + 2);
    }

    const int hG = h0 + rowL;
    float bvv[4][4];
#pragma unroll
    for (int mf = 0; mf < 4; mf++)
#pragma unroll
        for (int r = 0; r < 4; r++) bvv[mf][r] = bias[co0 + mf * 16 + 4 * l4 + r];

    bf16* dst = (co0 < 128) ? xh : kk;
    const int cod = co0 & 127;
#pragma unroll
    for (int mf = 0; mf < 4; mf++) {
#pragma unroll
        for (int nf = 0; nf < 4; nf++) {
            int w = w0 + nf * 16 + l15;
            bf16x4 v;
#pragma unroll
            for (int r = 0; r < 4; r++) v[r] = (bf16)(acc[mf][nf][r] + bvv[mf][r]);
            *(bf16x4*)&dst[((size_t)(b * H_ + hG) * W_ + w) * C_ + cod + mf * 16 + 4 * l4] = v;
        }
        if (co0 < 128) {
#pragma unroll
            for (int r = 0; r < 4; r++) {
                float s = 4.f * bvv[mf][r];
#pragma unroll
                for (int nf = 0; nf < 4; nf++) s += acc[mf][nf][r];
                s += __shfl_xor(s, 1, 64);
                s += __shfl_xor(s, 2, 64);
                s += __shfl_xor(s, 4, 64);
                s += __shfl_xor(s, 8, 64);
                if (l15 == 0)
                    atomicAdd(&meansum[b * 128 + co0 + mf * 16 + 4 * l4 + r], s);
            }
        }
    }
}

// ---------------------------------------------------------------------------
// K2: gating
// ---------------------------------------------------------------------------
__global__ void gate_kernel(const float* __restrict__ meansum,
                            const float* __restrict__ gw,
                            float* __restrict__ gate)
{
    int b = threadIdx.x;
    if (b >= 8) return;
    float l[3];
    for (int e = 0; e < 3; e++) {
        float s = 0.f;
        for (int c = 0; c < 128; c++) s += meansum[b * 128 + c] * gw[e * 128 + c];
        l[e] = s * (1.0f / 16384.0f);
    }
    float m = fmaxf(l[0], fmaxf(l[1], l[2]));
    float p0 = expf(l[0] - m), p1 = expf(l[1] - m), p2 = expf(l[2] - m);
    float s = p0 + p1 + p2;
    float w[3] = { p0 / s, p1 / s, p2 / s };
    int dm = 0;
    if (w[1] <= w[0]) dm = 1;
    if (w[2] <= w[dm]) dm = 2;
    for (int e = 0; e < 3; e++) gate[b * 3 + e] = (e == dm) ? 0.f : w[e];
}

// ---------------------------------------------------------------------------
// K3a/K3b: fem_b(0) -> [C][9-region] map
// ---------------------------------------------------------------------------
__global__ __launch_bounds__(128) void out2a_kernel(
    const float* __restrict__ c1b,
    const float* __restrict__ ew1, const float* __restrict__ eb1,
    const float* __restrict__ ew2, const float* __restrict__ eb2,
    float* __restrict__ sprod)
{
    const int e = blockIdx.x >> 7, c = blockIdx.x & 127;
    const int t = threadIdx.x;
    float xv = c1b[t], kv = c1b[128 + t];
    const float* w1 = ew1 + ((size_t)(e * 128 + c) * 128 + t) * 9;
    const float* w2 = ew2 + ((size_t)(e * 128 + c) * 128 + t) * 9;
    __shared__ float rA[9][128], rB[9][128];
#pragma unroll
    for (int tp = 0; tp < 9; tp++) { rA[tp][t] = xv * w1[tp]; rB[tp][t] = kv * w2[tp]; }
    __syncthreads();
    for (int s = 64; s > 0; s >>= 1) {
        if (t < s)
#pragma unroll
            for (int tp = 0; tp < 9; tp++) { rA[tp][t] += rA[tp][t + s]; rB[tp][t] += rB[tp][t + s]; }
        __syncthreads();
    }
    if (t < 9) {
        int rcl = t / 3, ccl = t % 3;
        float av = eb1[e * 128 + c], bv = eb2[e * 128 + c];
#pragma unroll
        for (int i = 0; i < 3; i++)
#pragma unroll
            for (int j = 0; j < 3; j++) {
                bool iok = (rcl == 1) || (rcl == 0 && i >= 1) || (rcl == 2 && i <= 1);
                bool jok = (ccl == 1) || (ccl == 0 && j >= 1) || (ccl == 2 && j <= 1);
                if (iok && jok) { av += rA[i * 3 + j][0]; bv += rB[i * 3 + j][0]; }
            }
        sprod[(size_t)(e * 128 + c) * 9 + t] = av * bv;
    }
}

__global__ __launch_bounds__(128) void out2b_kernel(
    const float* __restrict__ c1b, const float* __restrict__ gw,
    const float* __restrict__ sprod, const float* __restrict__ ew3,
    const float* __restrict__ eb3, float* __restrict__ out2map)
{
    const int c = blockIdx.x;
    const int t = threadIdx.x;
    __shared__ float red[27][128];
#pragma unroll
    for (int e = 0; e < 3; e++) {
        float wv = ew3[(size_t)(e * 128 + c) * 128 + t];
#pragma unroll
        for (int r = 0; r < 9; r++) red[e * 9 + r][t] = wv * sprod[(size_t)(e * 128 + t) * 9 + r];
    }
    __syncthreads();
    for (int s = 64; s > 0; s >>= 1) {
        if (t < s)
#pragma unroll
            for (int q = 0; q < 27; q++) red[q][t] += red[q][t + s];
        __syncthreads();
    }
    __shared__ float lsh[3];
    if (t < 3) {
        float s = 0.f;
        for (int cc = 0; cc < 128; cc++) s += c1b[cc] * gw[t * 128 + cc];
        lsh[t] = s;
    }
    __syncthreads();
    if (t == 0) {
        float l0 = lsh[0], l1 = lsh[1], l2 = lsh[2];
        float m = fmaxf(l0, fmaxf(l1, l2));
        float p0 = expf(l0 - m), p1 = expf(l1 - m), p2 = expf(l2 - m);
        float ssum = p0 + p1 + p2;
        float wv[3] = { p0 / ssum, p1 / ssum, p2 / ssum };
        int dm = 0;
        if (wv[1] <= wv[0]) dm = 1;
        if (wv[2] <= wv[dm]) dm = 2;
        wv[dm] = 0.f;
        for (int r = 0; r < 9; r++) {
            float o = c1b[c];
            for (int e = 0; e < 3; e++)
                o += wv[e] * (red[e * 9 + r][0] + eb3[e * 128 + c]);
            out2map[c * 9 + r] = o;
        }
    }
}

// ---------------------------------------------------------------------------
// K4: both experts per staged tile; counted-vmcnt XA/XB/K staging;
// P per-expert in LDS; single combined out write.
// ---------------------------------------------------------------------------
__global__ __launch_bounds__(512, 1) void expert_kernel(
    const bf16* __restrict__ xhp, const bf16* __restrict__ kkp,
    const bf16* __restrict__ we1, const float* __restrict__ eb1,
    const bf16* __restrict__ we2, const float* __restrict__ eb2,
    const bf16* __restrict__ w3, const float* __restrict__ eb3,
    const float* __restrict__ gate, const float* __restrict__ o2map,
    const float* __restrict__ x, float* __restrict__ out,
    const bf16* __restrict__ zbuf)
{
    const int bid = blockIdx.x;
    const int b = bid & 7, rp = (bid >> 3) & 63, pxh = bid >> 9;
    const int h0 = rp * 2, w0 = pxh * 64;
    const int t = threadIdx.x, lane = t & 63, ww = t >> 6;
    const int l15 = lane & 15, l4 = lane >> 4;
    const int rowL = ww & 1, co0 = (ww >> 1) * 32;
    __shared__ char sm[53248];
    char* XA = sm;
    char* XB = sm + 17408;
    char* KB = sm + 34816;
    char* dump = sm + 52224;

    float ga0 = gate[b * 3 + 0], ga1 = gate[b * 3 + 1], ga2 = gate[b * 3 + 2];
    int e0, e1; float w_e0, w_e1;
    if (ga0 > 0.f) { e0 = 0; w_e0 = ga0; if (ga1 > 0.f) { e1 = 1; w_e1 = ga1; } else { e1 = 2; w_e1 = ga2; } }
    else           { e0 = 1; w_e0 = ga1; e1 = 2; w_e1 = ga2; }

    f32x4 aa[2][2][4], ab[2][2][4];   // [expert][mf co][nf px]
#pragma unroll
    for (int pe = 0; pe < 2; pe++)
#pragma unroll
        for (int mf = 0; mf < 2; mf++)
#pragma unroll
            for (int nf = 0; nf < 4; nf++) {
                aa[pe][mf][nf] = (f32x4){0.f, 0.f, 0.f, 0.f};
                ab[pe][mf][nf] = (f32x4){0.f, 0.f, 0.f, 0.f};
            }

    stage_tile(xhp, zbuf, XA, dump, t, ww, b, h0, w0, 0);
    stage_tile(kkp, zbuf, KB, dump, t, ww, b, h0, w0, 0);

    char* Xcur = XA; char* Xoth = XB;
    for (int cb = 0; cb < 4; cb++) {
        // X(cb) landed (K(cb) = newest 3 stays in flight)
        WAITVM3;
        barrier_raw();
        // conv_a on Xcur: weights we1, experts e0,e1
#pragma unroll 1
        for (int dy = 0; dy < 3; dy++) {
            const int row_h = rowL + dy;
#pragma unroll
            for (int dx = 0; dx < 3; dx++) {
                const int tap = dy * 3 + dx;
                bf16x8 af0[2], af1[2];
#pragma unroll
                for (int mf = 0; mf < 2; mf++) {
                    af0[mf] = *(const bf16x8*)&we1[(size_t)((e0 * 9 + tap) * 128 + co0 + mf * 16 + l15) * 128 + cb * 32 + l4 * 8];
                    af1[mf] = *(const bf16x8*)&we1[(size_t)((e1 * 9 + tap) * 128 + co0 + mf * 16 + l15) * 128 + cb * 32 + l4 * 8];
                }
#pragma unroll
                for (int nf = 0; nf < 4; nf++) {
                    int wl = nf * 16 + l15 + dx;
                    int byt = (row_h * 272 + wl * 4 + (l4 ^ ((wl >> 1) & 3))) * 16;
                    bf16x8 bv = *(const bf16x8*)(Xcur + byt);
#pragma unroll
                    for (int mf = 0; mf < 2; mf++) {
                        aa[0][mf][nf] = __builtin_amdgcn_mfma_f32_16x16x32_bf16(af0[mf], bv, aa[0][mf][nf], 0, 0, 0);
                        aa[1][mf][nf] = __builtin_amdgcn_mfma_f32_16x16x32_bf16(af1[mf], bv, aa[1][mf][nf], 0, 0, 0);
                    }
                }
            }
        }
        // prefetch next X
        if (cb < 3) stage_tile(xhp, zbuf, Xoth, dump, t, ww, b, h0, w0, cb + 1);
        // K(cb) landed (X(cb+1) stays in flight)
        if (cb < 3) { WAITVM3; } else { WAITVM0; }
        barrier_raw();
        // conv_b on KB: weights we2
#pragma unroll 1
        for (int dy = 0; dy < 3; dy++) {
            const int row_h = rowL + dy;
#pragma unroll
            for (int dx = 0; dx < 3; dx++) {
                const int tap = dy * 3 + dx;
                bf16x8 af0[2], af1[2];
#pragma unroll
                for (int mf = 0; mf < 2; mf++) {
                    af0[mf] = *(const bf16x8*)&we2[(size_t)((e0 * 9 + tap) * 128 + co0 + mf * 16 + l15) * 128 + cb * 32 + l4 * 8];
                    af1[mf] = *(const bf16x8*)&we2[(size_t)((e1 * 9 + tap) * 128 + co0 + mf * 16 + l15) * 128 + cb * 32 + l4 * 8];
                }
#pragma unroll
                for (int nf = 0; nf < 4; nf++) {
                    int wl = nf * 16 + l15 + dx;
                    int byt = (row_h * 272 + wl * 4 + (l4 ^ ((wl >> 1) & 3))) * 16;
                    bf16x8 bv = *(const bf16x8*)(KB + byt);
#pragma unroll
                    for (int mf = 0; mf < 2; mf++) {
                        ab[0][mf][nf] = __builtin_amdgcn_mfma_f32_16x16x32_bf16(af0[mf], bv, ab[0][mf][nf], 0, 0, 0);
                        ab[1][mf][nf] = __builtin_amdgcn_mfma_f32_16x16x32_bf16(af1[mf], bv, ab[1][mf][nf], 0, 0, 0);
                    }
                }
            }
        }
        // all waves done reading KB, then restage it
        barrier_raw();
        if (cb < 3) stage_tile(kkp, zbuf, KB, dump, t, ww, b, h0, w0, cb + 1);
        char* tmp = Xcur; Xcur = Xoth; Xoth = tmp;
    }

    // P[pe] = (conv_a + b1) * (conv_b + b2) -> LDS [128px][128cc] bf16 (32 KB),
    // then 1x1 GEMM per expert; results held in eo0/eo1.
    f32x4 eoA[2][4], eoB[2][4];
#pragma unroll
    for (int mf = 0; mf < 2; mf++)
#pragma unroll
        for (int nf = 0; nf < 4; nf++) {
            eoA[mf][nf] = (f32x4){0.f, 0.f, 0.f, 0.f};
            eoB[mf][nf] = (f32x4){0.f, 0.f, 0.f, 0.f};
        }

#pragma unroll
    for (int pe = 0; pe < 2; pe++) {
        const int e = pe ? e1 : e0;
        const int ccb = co0 + 4 * l4;   // base (mf adds 16)
        float b1v[2][4], b2v[2][4];
#pragma unroll
        for (int mf = 0; mf < 2; mf++)
#pragma unroll
            for (int r = 0; r < 4; r++) {
                b1v[mf][r] = eb1[e * 128 + ccb + mf * 16 + r];
                b2v[mf][r] = eb2[e * 128 + ccb + mf * 16 + r];
            }
#pragma unroll
        for (int mf = 0; mf < 2; mf++)
#pragma unroll
            for (int nf = 0; nf < 4; nf++) {
                int px = rowL * 64 + nf * 16 + l15;
                int cc = ccb + mf * 16;
                bf16x4 pv;
#pragma unroll
                for (int r = 0; r < 4; r++)
                    pv[r] = (bf16)((aa[pe][mf][nf][r] + b1v[mf][r]) * (ab[pe][mf][nf][r] + b2v[mf][r]));
                int byt = px * 256 + (((cc >> 3) ^ (px & 15)) * 16) + (cc & 7) * 2;
                *(bf16x4*)(sm + byt) = pv;
            }
        barrier_raw();

        // 1x1 GEMM over K=128 from P
#pragma unroll 1
        for (int ks = 0; ks < 4; ks++) {
            bf16x8 a3[2];
#pragma unroll
            for (int mf = 0; mf < 2; mf++)
                a3[mf] = *(const bf16x8*)&w3[(size_t)(e * 128 + co0 + mf * 16 + l15) * 128 + ks * 32 + l4 * 8];
#pragma unroll
            for (int nf = 0; nf < 4; nf++) {
                int px = rowL * 64 + nf * 16 + l15;
                int byt = px * 256 + (((ks * 4 + l4) ^ (px & 15)) * 16);
                bf16x8 bp = *(const bf16x8*)(sm + byt);
#pragma unroll
                for (int mf = 0; mf < 2; mf++) {
                    if (pe == 0)
                        eoA[mf][nf] = __builtin_amdgcn_mfma_f32_16x16x32_bf16(a3[mf], bp, eoA[mf][nf], 0, 0, 0);
                    else
                        eoB[mf][nf] = __builtin_amdgcn_mfma_f32_16x16x32_bf16(a3[mf], bp, eoB[mf][nf], 0, 0, 0);
                }
            }
        }
        barrier_raw();   // P region reused by next expert
    }

    // epilogue: single coalesced write
    const int h = h0 + rowL;
    const int rcl = (h == 0) ? 0 : ((h == 127) ? 2 : 1);
#pragma unroll
    for (int mf = 0; mf < 2; mf++) {
        int cbase = co0 + mf * 16 + 4 * l4;
        float b30[4], b31[4];
#pragma unroll
        for (int r = 0; r < 4; r++) {
            b30[r] = eb3[e0 * 128 + cbase + r];
            b31[r] = eb3[e1 * 128 + cbase + r];
        }
#pragma unroll
        for (int nf = 0; nf < 4; nf++) {
            int w = w0 + nf * 16 + l15;
            bf16x4 xv = *(const bf16x4*)&xhp[((size_t)(b * H_ + h) * W_ + w) * C_ + cbase];
            int ccl = (w == 0) ? 0 : ((w == 127) ? 2 : 1);
#pragma unroll
            for (int r = 0; r < 4; r++) {
                size_t gi = ((size_t)(b * C_ + cbase + r) * H_ + h) * W_ + w;
                out[gi] = (float)xv[r] + x[gi] + o2map[(cbase + r) * 9 + rcl * 3 + ccl]
                        + w_e0 * (eoA[mf][nf][r] + b30[r])
                        + w_e1 * (eoB[mf][nf][r] + b31[r]);
            }
        }
    }
}

// ---------------------------------------------------------------------------
extern "C" void kernel_launch(void* const* d_in, const int* in_sizes, int n_in,
                              void* d_out, int out_size, void* d_ws, size_t ws_size,
                              hipStream_t stream)
{
    const float* x      = (const float*)d_in[0];
    const float* a_c1w  = (const float*)d_in[1];
    const float* a_c1b  = (const float*)d_in[2];
    const float* a_gw   = (const float*)d_in[3];
    const float* a_ew1  = (const float*)d_in[4];
    const float* a_eb1  = (const float*)d_in[5];
    const float* a_ew2  = (const float*)d_in[6];
    const float* a_eb2  = (const float*)d_in[7];
    const float* a_ew3  = (const float*)d_in[8];
    const float* a_eb3  = (const float*)d_in[9];
    const float* b_c1b  = (const float*)d_in[11];
    const float* b_gw   = (const float*)d_in[12];
    const float* b_ew1  = (const float*)d_in[13];
    const float* b_eb1  = (const float*)d_in[14];
    const float* b_ew2  = (const float*)d_in[15];
    const float* b_eb2  = (const float*)d_in[16];
    const float* b_ew3  = (const float*)d_in[17];
    const float* b_eb3  = (const float*)d_in[18];
    float* out = (float*)d_out;

    char* ws = (char*)d_ws;
    bf16*  xh      = (bf16*)(ws);                      // 33554432 B
    bf16*  kk      = (bf16*)(ws + 33554432);           // 33554432 B
    bf16*  wT1     = (bf16*)(ws + 67108864);           // 589824 B
    bf16*  wTe1    = (bf16*)(ws + 67698688);           // 884736 B
    bf16*  wTe2    = (bf16*)(ws + 68583424);           // 884736 B
    bf16*  wT3     = (bf16*)(ws + 69468160);           // 98304 B
    float* meansum = (float*)(ws + 69566464);          // 4096 B
    float* gate    = (float*)(ws + 69570560);          // 128 B
    float* o2map   = (float*)(ws + 69570688);          // 4608 B
    bf16*  zbuf    = (bf16*)(ws + 69575296);           // 256 B
    float* sprod   = (float*)(ws + 69575552);          // 13824 B

    bf16* xa = (bf16*)d_out;   // |x| NHWC bf16 scratch (overwritten last)

    hipMemsetAsync(ws + 69566464, 0, 4096, stream);        // meansum
    hipMemsetAsync(ws + 69575296, 0, 256, stream);         // zero buffer

    wprep1_kernel<<<(256 * 128 * 9 + 255) / 256, 256, 0, stream>>>(a_c1w, wT1);
    wprepE_kernel<<<(3 * 128 * 128 * 9 + 255) / 256, 256, 0, stream>>>(a_ew1, wTe1);
    wprepE_kernel<<<(3 * 128 * 128 * 9 + 255) / 256, 256, 0, stream>>>(a_ew2, wTe2);
    wprep3_kernel<<<(3 * 128 * 128 + 255) / 256, 256, 0, stream>>>(a_ew3, wT3);

    xpose_kernel<<<dim3(4, 128, 8), 256, 0, stream>>>(x, xa);

    conv1_kernel<<<1024, 512, 0, stream>>>(xa, wT1, a_c1b, xh, kk, meansum, zbuf);

    gate_kernel<<<1, 64, 0, stream>>>(meansum, a_gw, gate);
    out2a_kernel<<<384, 128, 0, stream>>>(b_c1b, b_ew1, b_eb1, b_ew2, b_eb2, sprod);
    out2b_kernel<<<128, 128, 0, stream>>>(b_c1b, b_gw, sprod, b_ew3, b_eb3, o2map);

    expert_kernel<<<1024, 512, 0, stream>>>(
        xh, kk, wTe1, a_eb1, wTe2, a_eb2, wT3, a_eb3, gate, o2map, x, out, zbuf);
}